// Round 4
// baseline (19715.825 us; speedup 1.0000x reference)
//
#include <hip/hip_runtime.h>
#include <math.h>

typedef unsigned short u16;
typedef __attribute__((ext_vector_type(8))) __bf16 bf16x8;
typedef __attribute__((ext_vector_type(4))) float floatx4;

#define EPI_BIAS  1
#define EPI_RELU  2
#define EPI_EMBED 8

__device__ __forceinline__ float bf2f(u16 u) {
    union { unsigned int i; float f; } v; v.i = ((unsigned int)u) << 16; return v.f;
}
__device__ __forceinline__ u16 f2bf(float f) {
    union { float f; unsigned int i; } v; v.f = f;
    unsigned int x = v.i;
    return (u16)((x + 0x7fffu + ((x >> 16) & 1u)) >> 16);
}
// fp64 positional encoding (epilogue-only, embed GEMM; negligible cost)
__device__ __forceinline__ float posenc(int s, int c) {
    double e = exp((double)(c & 1022) * (-9.210340371976184 / 1024.0));
    double ang = (double)s * e;
    return (float)((c & 1) ? cos(ang) : sin(ang));
}

// ------- transpose+convert: in fp32 [R][C] -> out bf16 [C][R] (+lo term) -------
template<bool SPLIT>
__global__ __launch_bounds__(256) void transpose_f2b(
    const float* __restrict__ in, u16* __restrict__ oh, u16* __restrict__ ol,
    int R, int C) {
    __shared__ float tile[32][33];
    int bx = blockIdx.x * 32, by = blockIdx.y * 32;
    int tx = threadIdx.x & 31, ty = threadIdx.x >> 5; // ty 0..7
    #pragma unroll
    for (int i = ty; i < 32; i += 8) tile[i][tx] = in[(size_t)(by + i) * C + bx + tx];
    __syncthreads();
    #pragma unroll
    for (int i = ty; i < 32; i += 8) {
        float f = tile[tx][i];
        u16 hi = f2bf(f);
        oh[(size_t)(bx + i) * R + by + tx] = hi;
        if (SPLIT) ol[(size_t)(bx + i) * R + by + tx] = f2bf(f - bf2f(hi));
    }
}

// ---------------- GEMM: C[M][N] = A[M][K] * Bt[N][K]^T, MFMA bf16 ----------------
// AMODE: 0 = A bf16(u16). 1 = A fp32 -> bf16 hi. 2 = A fp32 -> bf16 lo (f - hi).
template<int AMODE, int EPI, bool ACCUM, bool WF, bool WB>
__global__ __launch_bounds__(256) void gemm_k(
    const void* __restrict__ Ap, const u16* __restrict__ Bt,
    const float* __restrict__ bias,
    float* __restrict__ outF, u16* __restrict__ outB,
    int M, int N, int K) {
    __shared__ alignas(16) u16 As[128 * 32];
    __shared__ alignas(16) u16 Bs[128 * 32];
    const int tid = threadIdx.x;
    const int wave = tid >> 6, lane = tid & 63;
    const int l16 = lane & 15, quad = lane >> 4;
    const int bm = blockIdx.x * 128, bn = blockIdx.y * 128;
    const int wm = (wave & 1) * 64, wn = (wave >> 1) * 64;
    const int sr = tid >> 2, sc = (tid & 3) * 8;

    const u16* Abf = (const u16*)Ap;
    const float* Af = (const float*)Ap;

    floatx4 acc[4][4];
    floatx4 zero = {0.0f, 0.0f, 0.0f, 0.0f};
    #pragma unroll
    for (int i = 0; i < 4; ++i)
        #pragma unroll
        for (int j = 0; j < 4; ++j) acc[i][j] = zero;

    for (int k0 = 0; k0 < K; k0 += 32) {
        // ---- stage A tile (128 x 32) ----
        if (AMODE == 0) {
            #pragma unroll
            for (int p = 0; p < 2; ++p) {
                uint4 v = *(const uint4*)(Abf + (size_t)(bm + sr + 64 * p) * K + k0 + sc);
                *(uint4*)&As[(sr + 64 * p) * 32 + sc] = v;
            }
        } else {
            #pragma unroll
            for (int p = 0; p < 2; ++p) {
                const float* g = Af + (size_t)(bm + sr + 64 * p) * K + k0 + sc;
                union { u16 u[8]; uint4 v; } tmp;
                #pragma unroll
                for (int j = 0; j < 8; ++j) {
                    float f = g[j];
                    u16 h = f2bf(f);                 // hi
                    if (AMODE == 2) h = f2bf(f - bf2f(h)); // lo (Sterbenz-exact residual)
                    tmp.u[j] = h;
                }
                *(uint4*)&As[(sr + 64 * p) * 32 + sc] = tmp.v;
            }
        }
        // ---- stage B tile (128 x 32) from Bt[N][K] (bf16) ----
        #pragma unroll
        for (int p = 0; p < 2; ++p) {
            uint4 v = *(const uint4*)(Bt + (size_t)(bn + sr + 64 * p) * K + k0 + sc);
            *(uint4*)&Bs[(sr + 64 * p) * 32 + sc] = v;
        }
        __syncthreads();
        bf16x8 af[4], bfr[4];
        #pragma unroll
        for (int i = 0; i < 4; ++i) af[i] = *(const bf16x8*)&As[(wm + i * 16 + l16) * 32 + quad * 8];
        #pragma unroll
        for (int j = 0; j < 4; ++j) bfr[j] = *(const bf16x8*)&Bs[(wn + j * 16 + l16) * 32 + quad * 8];
        #pragma unroll
        for (int i = 0; i < 4; ++i)
            #pragma unroll
            for (int j = 0; j < 4; ++j)
                acc[i][j] = __builtin_amdgcn_mfma_f32_16x16x32_bf16(af[i], bfr[j], acc[i][j], 0, 0, 0);
        __syncthreads();
    }

    // ---- epilogue (C/D map: col=lane&15, row=quad*4+reg) ----
    #pragma unroll
    for (int i = 0; i < 4; ++i) {
        #pragma unroll
        for (int r = 0; r < 4; ++r) {
            int row = bm + wm + i * 16 + quad * 4 + r;
            #pragma unroll
            for (int j = 0; j < 4; ++j) {
                int col = bn + wn + j * 16 + l16;
                float v = acc[i][j][r];
                if (EPI & EPI_BIAS) v += bias[col];
                if (ACCUM) v += outF[(size_t)row * N + col];
                if (EPI & EPI_EMBED) { v = v * 32.0f + posenc(row & 2047, col); }
                if (EPI & EPI_RELU) v = fmaxf(v, 0.0f);
                if (WF) outF[(size_t)row * N + col] = v;
                if (WB) outB[(size_t)row * N + col] = f2bf(v);
            }
        }
    }
}

// ---------------- attention: fp32 qkv[b][s][3072] -> ctx bf16 [8192][1024] ----------------
// block = 256 thr = 4 waves; each wave = one q row; blockIdx: bh * 512 + qt
__global__ __launch_bounds__(256) void attn_k(
    const float* __restrict__ qkv, u16* __restrict__ ctx) {
    __shared__ alignas(16) float Ks[64 * 68];
    __shared__ alignas(16) float probs[4][2048];
    __shared__ alignas(16) float qs[4][64];
    const int tid = threadIdx.x, wave = tid >> 6, lane = tid & 63;
    const int bh = blockIdx.x >> 9;
    const int qt = blockIdx.x & 511;
    const int b = bh >> 4, h = bh & 15;
    const size_t base = (size_t)b * 2048 * 3072;
    const int qrow = qt * 4 + wave;
    const int koffK = 1024 + h * 64;
    const int koffV = 2048 + h * 64;

    qs[wave][lane] = qkv[base + (size_t)qrow * 3072 + h * 64 + lane];
    __syncthreads();

    // phase 1: raw scores
    for (int c = 0; c < 2048; c += 64) {
        {
            const int r = tid >> 2, pf = (tid & 3) * 16;
            const float* g = qkv + base + (size_t)(c + r) * 3072 + koffK + pf;
            float4 v0 = ((const float4*)g)[0];
            float4 v1 = ((const float4*)g)[1];
            float4 v2 = ((const float4*)g)[2];
            float4 v3 = ((const float4*)g)[3];
            float* dd = &Ks[r * 68 + pf];
            ((float4*)dd)[0] = v0; ((float4*)dd)[1] = v1;
            ((float4*)dd)[2] = v2; ((float4*)dd)[3] = v3;
        }
        __syncthreads();
        const float* kr = &Ks[lane * 68];
        const float* qq = qs[wave];
        float a = 0.0f;
        #pragma unroll
        for (int d = 0; d < 64; d += 4) {
            float4 kv = *(const float4*)&kr[d];
            float4 qv = *(const float4*)&qq[d];
            a += kv.x * qv.x + kv.y * qv.y + kv.z * qv.z + kv.w * qv.w;
        }
        probs[wave][c + lane] = a * 0.125f;
        __syncthreads();
    }

    // phase 2: per-wave softmax (unnormalized; fold 1/l at end)
    float sc[32];
    float m = -1e30f, l = 0.0f;
    #pragma unroll
    for (int i = 0; i < 32; ++i) { sc[i] = probs[wave][i * 64 + lane]; m = fmaxf(m, sc[i]); }
    for (int off = 32; off; off >>= 1) m = fmaxf(m, __shfl_xor(m, off));
    #pragma unroll
    for (int i = 0; i < 32; ++i) { float e = __expf(sc[i] - m); sc[i] = e; l += e; }
    for (int off = 32; off; off >>= 1) l += __shfl_xor(l, off);
    #pragma unroll
    for (int i = 0; i < 32; ++i) probs[wave][i * 64 + lane] = sc[i];
    float rl = 1.0f / l;
    __syncthreads();

    // phase 3: PV; lane owns output dim = lane
    float outv = 0.0f;
    for (int c = 0; c < 2048; c += 64) {
        {
            const int r = tid >> 2, pf = (tid & 3) * 16;
            const float* g = qkv + base + (size_t)(c + r) * 3072 + koffV + pf;
            float4 v0 = ((const float4*)g)[0];
            float4 v1 = ((const float4*)g)[1];
            float4 v2 = ((const float4*)g)[2];
            float4 v3 = ((const float4*)g)[3];
            float* dd = &Ks[r * 68 + pf];
            ((float4*)dd)[0] = v0; ((float4*)dd)[1] = v1;
            ((float4*)dd)[2] = v2; ((float4*)dd)[3] = v3;
        }
        __syncthreads();
        const float* pv = &probs[wave][c];
        #pragma unroll
        for (int kk = 0; kk < 64; kk += 4) {
            float4 p4 = *(const float4*)&pv[kk];
            outv += p4.x * Ks[(kk + 0) * 68 + lane];
            outv += p4.y * Ks[(kk + 1) * 68 + lane];
            outv += p4.z * Ks[(kk + 2) * 68 + lane];
            outv += p4.w * Ks[(kk + 3) * 68 + lane];
        }
        __syncthreads();
    }
    ctx[(size_t)(b * 2048 + qrow) * 1024 + h * 64 + lane] = f2bf(outv * rl);
}

// ---------------- layernorm, in-place on fp32 h; one block per row ----------------
__global__ __launch_bounds__(256) void ln_k(
    float* __restrict__ h, const float* __restrict__ g, const float* __restrict__ bb) {
    const int row = blockIdx.x, tid = threadIdx.x;
    const int wave = tid >> 6, lane = tid & 63;
    float4 v = *(const float4*)(h + (size_t)row * 1024 + tid * 4);
    float x[4] = {v.x, v.y, v.z, v.w};
    float s = x[0] + x[1] + x[2] + x[3];
    float s2 = x[0] * x[0] + x[1] * x[1] + x[2] * x[2] + x[3] * x[3];
    for (int off = 32; off; off >>= 1) { s += __shfl_xor(s, off); s2 += __shfl_xor(s2, off); }
    __shared__ float red[8];
    if (lane == 0) { red[wave] = s; red[4 + wave] = s2; }
    __syncthreads();
    s = red[0] + red[1] + red[2] + red[3];
    s2 = red[4] + red[5] + red[6] + red[7];
    float mu = s * (1.0f / 1024.0f);
    float var = s2 * (1.0f / 1024.0f) - mu * mu;
    float rs = rsqrtf(var + 1e-5f);
    float4 gg = *(const float4*)(g + tid * 4);
    float4 bp = *(const float4*)(bb + tid * 4);
    float4 o;
    o.x = (x[0] - mu) * rs * gg.x + bp.x;
    o.y = (x[1] - mu) * rs * gg.y + bp.y;
    o.z = (x[2] - mu) * rs * gg.z + bp.z;
    o.w = (x[3] - mu) * rs * gg.w + bp.w;
    *(float4*)(h + (size_t)row * 1024 + tid * 4) = o;
}

// ---------------- orchestration ----------------
extern "C" void kernel_launch(void* const* d_in, const int* in_sizes, int n_in,
                              void* d_out, int out_size, void* d_ws, size_t ws_size,
                              hipStream_t stream) {
    // ALL inputs are float32 (reference dtypes); round 2/3 NaN = reading fp32 as bf16.
    const float* x     = (const float*)d_in[0];
    const float* in_W  = (const float*)d_in[1];
    const float* in_b  = (const float*)d_in[2];
    const float* qkv_W = (const float*)d_in[3];
    const float* qkv_b = (const float*)d_in[4];
    const float* out_W = (const float*)d_in[5];
    const float* out_b = (const float*)d_in[6];
    const float* ln1_g = (const float*)d_in[7];
    const float* ln1_b = (const float*)d_in[8];
    const float* ln2_g = (const float*)d_in[9];
    const float* ln2_b = (const float*)d_in[10];
    const float* ff1_W = (const float*)d_in[11];
    const float* ff1_b = (const float*)d_in[12];
    const float* ff2_W = (const float*)d_in[13];
    const float* ff2_b = (const float*)d_in[14];
    const float* fin_g = (const float*)d_in[15];
    const float* fin_b = (const float*)d_in[16];
    const float* op_W  = (const float*)d_in[17];
    const float* op_b  = (const float*)d_in[18];

    // Workspace 160 MB (<=169 MB proven available in rounds 2/3)
    size_t off = 0;
    char* wsb = (char*)d_ws;
    auto alloc = [&](size_t bytes) { void* p = wsb + off; off += (bytes + 255) & ~(size_t)255; return p; };
    u16*   BtH  = (u16*)alloc((size_t)4096 * 1024 * 2);      // 8 MB  rotating B^T (hi)
    u16*   BtL  = (u16*)alloc((size_t)3072 * 1024 * 2);      // 6 MB  rotating B^T (lo, split GEMMs)
    float* hbuf = (float*)alloc((size_t)8192 * 1024 * 4);    // 32 MB fp32 hidden (in-place resid+LN)
    float* qkvb = (float*)alloc((size_t)8192 * 3072 * 4);    // 96 MB fp32 qkv / bf16 ff scratch
    u16*   ctxb = (u16*)alloc((size_t)8192 * 1024 * 2);      // 16 MB bf16 ctx
    if (off > ws_size) return;

    dim3 tb(256);

    // ---- embed: h = (x @ in_W + b)*32 + posenc, double-split (fp32-accurate h0) ----
    transpose_f2b<true><<<dim3(32, 16), tb, 0, stream>>>(in_W, BtH, BtL, 512, 1024);
    gemm_k<1, 0, false, true, false><<<dim3(64, 8), tb, 0, stream>>>(
        x, BtH, nullptr, hbuf, nullptr, 8192, 1024, 512);                       // hi*hi
    gemm_k<1, 0, true, true, false><<<dim3(64, 8), tb, 0, stream>>>(
        x, BtL, nullptr, hbuf, nullptr, 8192, 1024, 512);                       // hi*lo
    gemm_k<2, EPI_BIAS | EPI_EMBED, true, true, false><<<dim3(64, 8), tb, 0, stream>>>(
        x, BtH, in_b, hbuf, nullptr, 8192, 1024, 512);                          // lo*hi + epilogue

    for (int L = 0; L < 4; ++L) {
        // ---- qkv ----
        if (L == 0) {
            // double-split: layer-0 scores are sigma~1024 (softmax ~ argmax) -> need ~fp32 q,k
            transpose_f2b<true><<<dim3(96, 32), tb, 0, stream>>>(
                qkv_W, BtH, BtL, 1024, 3072);
            gemm_k<1, 0, false, true, false><<<dim3(64, 24), tb, 0, stream>>>(
                hbuf, BtH, nullptr, qkvb, nullptr, 8192, 3072, 1024);
            gemm_k<1, 0, true, true, false><<<dim3(64, 24), tb, 0, stream>>>(
                hbuf, BtL, nullptr, qkvb, nullptr, 8192, 3072, 1024);
            gemm_k<2, EPI_BIAS, true, true, false><<<dim3(64, 24), tb, 0, stream>>>(
                hbuf, BtH, qkv_b, qkvb, nullptr, 8192, 3072, 1024);
        } else {
            transpose_f2b<false><<<dim3(96, 32), tb, 0, stream>>>(
                qkv_W + (size_t)L * 1024 * 3072, BtH, nullptr, 1024, 3072);
            gemm_k<1, EPI_BIAS, false, true, false><<<dim3(64, 24), tb, 0, stream>>>(
                hbuf, BtH, qkv_b + (size_t)L * 3072, qkvb, nullptr, 8192, 3072, 1024);
        }
        // ---- attention ----
        attn_k<<<dim3(32768), tb, 0, stream>>>(qkvb, ctxb);
        // ---- out-proj + residual (ACCUM into h) + LN in-place ----
        transpose_f2b<false><<<dim3(32, 32), tb, 0, stream>>>(
            out_W + (size_t)L * 1024 * 1024, BtH, nullptr, 1024, 1024);
        gemm_k<0, EPI_BIAS, true, true, false><<<dim3(64, 8), tb, 0, stream>>>(
            ctxb, BtH, out_b + (size_t)L * 1024, hbuf, nullptr, 8192, 1024, 1024);
        ln_k<<<8192, tb, 0, stream>>>(hbuf, ln1_g + (size_t)L * 1024, ln1_b + (size_t)L * 1024);
        // ---- FF ----
        transpose_f2b<false><<<dim3(128, 32), tb, 0, stream>>>(
            ff1_W + (size_t)L * 1024 * 4096, BtH, nullptr, 1024, 4096);
        gemm_k<1, EPI_BIAS | EPI_RELU, false, false, true><<<dim3(64, 32), tb, 0, stream>>>(
            hbuf, BtH, ff1_b + (size_t)L * 4096, nullptr, (u16*)qkvb, 8192, 4096, 1024);
        transpose_f2b<false><<<dim3(32, 128), tb, 0, stream>>>(
            ff2_W + (size_t)L * 4096 * 1024, BtH, nullptr, 4096, 1024);
        gemm_k<0, EPI_BIAS, true, true, false><<<dim3(64, 8), tb, 0, stream>>>(
            (u16*)qkvb, BtH, ff2_b + (size_t)L * 1024, hbuf, nullptr, 8192, 1024, 4096);
        ln_k<<<8192, tb, 0, stream>>>(hbuf, ln2_g + (size_t)L * 1024, ln2_b + (size_t)L * 1024);
    }

    // ---- final LN (in-place) + output projection -> fp32 d_out ----
    ln_k<<<8192, tb, 0, stream>>>(hbuf, fin_g, fin_b);
    transpose_f2b<false><<<dim3(32, 32), tb, 0, stream>>>(op_W, BtH, nullptr, 1024, 1024);
    gemm_k<1, EPI_BIAS, false, true, false><<<dim3(64, 8), tb, 0, stream>>>(
        hbuf, BtH, op_b, (float*)d_out, nullptr, 8192, 1024, 1024);
}